// Round 2
// baseline (325.504 us; speedup 1.0000x reference)
//
#include <hip/hip_runtime.h>
#include <math.h>

#define NN 512
#define HD 64
#define EPSV 1e-5f

typedef unsigned short u16;
typedef short s4v __attribute__((ext_vector_type(4)));
typedef short s8v __attribute__((ext_vector_type(8)));
typedef float f4v __attribute__((ext_vector_type(4)));

// ======================= multi-mode pipelined GEMM ========================
// 32(M) x 64(N) tile, 256 threads, BK=64, split-bf16 3-term MFMA
// (A*B ~= Ahi*Bhi + Ahi*Blo + Alo*Bhi, rel err ~2^-16).
// R2: B operands of launch-2/3 GEMMs come from PRE-SPLIT TRANSPOSED bf16
// planes (Bth/Btl, [n][Bkp]); producers write them from their epilogues
// (Cth/Ctl). Removes per-block split VALU + conflicted scalar u16
// transpose stores from 1088 tile-iters.
struct GD {
  const float *A, *A2, *A3, *A4;
  const int* I;
  const float *B, *bias;
  float* C;
  const u16 *Bth, *Btl;   // pre-split transposed B planes [n][Bkp]
  u16 *Cth, *Ctl;         // optional epilogue: write C^T planes [col][Ckp]
  int Bkp, Ckp;
  int M, K, Nn, mode, act;
};

// LDS: Ah 4608 + Al 4608 + Bh 8704 + Bl 8704 + extra 2176 = 28800
#define GEMM_SMEM 28800
#define MEGA_SMEM 38656

__device__ __forceinline__ void split_bf16(float x, u16& h, u16& l) {
  unsigned xb = __float_as_uint(x);
  float hf = __uint_as_float(xb & 0xffff0000u);
  h = (u16)(xb >> 16);
  l = (u16)(__float_as_uint(x - hf) >> 16);
}

__device__ __forceinline__ void gemm_body(char* smem, const GD& d, int bx, int by) {
  u16 (*Ah)[72] = (u16(*)[72])smem;
  u16 (*Al)[72] = (u16(*)[72])(smem + 4608);
  u16 (*Bh)[68] = (u16(*)[68])(smem + 9216);
  u16 (*Bl)[68] = (u16(*)[68])(smem + 9216 + 8704);
  char* extra = smem + 26624;
  int* nbl = (int*)extra;                 // mode 2: 32 rows x {n0,n1,valid}
  float* wscl = (float*)extra;            // mode 4: exp(wsc) (512)
  float* rowsuml = wscl + 512;            // mode 4: 32

  const int t = threadIdx.x;
  const int rowbase = by * 32, colbase = bx * 64;
  const int K = d.K, Nn = d.Nn, mode = d.mode, M = d.M;
  if (rowbase >= M) return;

  if (mode == 2) {
    int wave = t >> 6, lane = t & 63;
    for (int rr = wave; rr < 32; rr += 4) {
      int row = rowbase + rr;
      int n0 = -1, n1 = -1, cnt = 0;
      for (int c = 0; c < 8; ++c) {
        unsigned long long mm = __ballot(d.I[row * NN + c * 64 + lane] != 0);
        cnt += (int)__popcll(mm);
        if (n0 < 0 && mm) { n0 = c * 64 + (int)__builtin_ctzll(mm); mm &= mm - 1; }
        if (n1 < 0 && mm) { n1 = c * 64 + (int)__builtin_ctzll(mm); }
      }
      if (lane == 0) { nbl[rr * 3] = n0; nbl[rr * 3 + 1] = n1; nbl[rr * 3 + 2] = (cnt >= 2); }
    }
    __syncthreads();
  } else if (mode == 4) {
    wscl[t] = d.A2[t];
    wscl[256 + t] = d.A2[256 + t];
    __syncthreads();
  }

  float4 aR[2], bR[4];
  s8v bp[4];                    // plane path: [0..1]=hi, [2..3]=lo
  float rs0 = 0.f, rs1 = 0.f;   // mode-4 row sums

  auto loadA = [&](int k0) {
#pragma unroll
    for (int j = 0; j < 2; ++j) {
      int idx = t + j * 256;
      int r = idx >> 4, c0 = (idx & 15) * 4;
      int row = rowbase + r, gk = k0 + c0;
      float4 v4 = make_float4(0.f, 0.f, 0.f, 0.f);
      if (mode == 0) {
        if (row < M && gk < K) v4 = *(const float4*)&d.A[(size_t)row * K + gk];
      } else if (mode == 1) {
        if (gk < 256) v4 = *(const float4*)&d.A[row * 256 + gk];
        else v4 = *(const float4*)&d.A2[row * 256 + gk - 256];
      } else if (mode == 2) {
        int seg = gk >> 8;
        int src = (seg == 0) ? row : (nbl[r * 3 + 2] ? nbl[r * 3 + seg - 1] : -1);
        if (src >= 0) v4 = *(const float4*)&d.A[src * 256 + (gk & 255)];
      } else if (mode == 3) {
        if (gk + 3 < 256) v4 = *(const float4*)&d.A[row * 256 + gk];
        else if (gk >= 256 && gk + 3 < 320) v4 = *(const float4*)&d.A2[gk - 256];
        else if (gk >= 320 && gk + 3 < 384) v4 = *(const float4*)&d.A3[row * 64 + gk - 320];
        else if (gk == 384) v4.x = (row < 64) ? d.A4[row] : 0.f;
      } else {  // mode 4
        int4 a4 = *(const int4*)&d.I[row * NN + gk];
        v4.x = a4.x ? wscl[gk + 0] : 0.f;
        v4.y = a4.y ? wscl[gk + 1] : 0.f;
        v4.z = a4.z ? wscl[gk + 2] : 0.f;
        v4.w = a4.w ? wscl[gk + 3] : 0.f;
        float ss = v4.x + v4.y + v4.z + v4.w;
        if (j == 0) rs0 += ss; else rs1 += ss;
      }
      aR[j] = v4;
    }
  };
  auto loadB = [&](int k0) {
    if (d.Bth) {
#pragma unroll
      for (int j = 0; j < 2; ++j) {
        int idx = t + j * 256;
        int n = idx >> 3, kb = (idx & 7) * 8;
        size_t base = (size_t)(colbase + n) * d.Bkp + k0 + kb;
        bp[j] = *(const s8v*)&d.Bth[base];
        bp[2 + j] = *(const s8v*)&d.Btl[base];
      }
    } else {
#pragma unroll
      for (int j = 0; j < 4; ++j) {
        int idx = t + j * 256;
        int r = idx >> 4, c0 = (idx & 15) * 4;
        int gk = k0 + r;
        float4 v4 = make_float4(0.f, 0.f, 0.f, 0.f);
        if (gk < K) v4 = *(const float4*)&d.B[(size_t)gk * Nn + colbase + c0];
        bR[j] = v4;
      }
    }
  };
  auto stos = [&]() {
#pragma unroll
    for (int j = 0; j < 2; ++j) {
      int idx = t + j * 256;
      int r = idx >> 4, c0 = (idx & 15) * 4;
      float v[4] = {aR[j].x, aR[j].y, aR[j].z, aR[j].w};
      u16 h[4], l[4];
#pragma unroll
      for (int e = 0; e < 4; ++e) split_bf16(v[e], h[e], l[e]);
      *(short4*)&Ah[r][c0] = make_short4((short)h[0], (short)h[1], (short)h[2], (short)h[3]);
      *(short4*)&Al[r][c0] = make_short4((short)l[0], (short)l[1], (short)l[2], (short)l[3]);
    }
    if (d.Bth) {
#pragma unroll
      for (int j = 0; j < 2; ++j) {
        int idx = t + j * 256;
        int n = idx >> 3, kb = (idx & 7) * 8;
        *(s8v*)&Bh[n][kb] = bp[j];
        *(s8v*)&Bl[n][kb] = bp[2 + j];
      }
    } else {
#pragma unroll
      for (int j = 0; j < 4; ++j) {
        int idx = t + j * 256;
        int r = idx >> 4, c0 = (idx & 15) * 4;
        float v[4] = {bR[j].x, bR[j].y, bR[j].z, bR[j].w};
#pragma unroll
        for (int e = 0; e < 4; ++e) {
          u16 h, l;
          split_bf16(v[e], h, l);
          Bh[c0 + e][r] = h;
          Bl[c0 + e][r] = l;
        }
      }
    }
  };

  f4v acc0 = {0.f, 0.f, 0.f, 0.f};
  f4v acc1 = {0.f, 0.f, 0.f, 0.f};

  const int w4 = t >> 6;
  const int lrow = t & 15;
  const int lk = ((t & 63) >> 4) * 8;

  int iters = (K + 63) >> 6;
  loadA(0); loadB(0);
  for (int it = 0; it < iters; ++it) {
    stos();
    __syncthreads();
    if (it + 1 < iters) { loadA((it + 1) << 6); loadB((it + 1) << 6); }
    const u16* bhrow = Bh[w4 * 16 + lrow];
    const u16* blrow = Bl[w4 * 16 + lrow];
#pragma unroll
    for (int ks = 0; ks < 2; ++ks) {
      int ko = ks * 32 + lk;
      s4v bh_0 = *(const s4v*)&bhrow[ko];
      s4v bh_1 = *(const s4v*)&bhrow[ko + 4];
      s4v bl_0 = *(const s4v*)&blrow[ko];
      s4v bl_1 = *(const s4v*)&blrow[ko + 4];
      s8v bh = __builtin_shufflevector(bh_0, bh_1, 0, 1, 2, 3, 4, 5, 6, 7);
      s8v bl = __builtin_shufflevector(bl_0, bl_1, 0, 1, 2, 3, 4, 5, 6, 7);
      {
        s8v ah = *(const s8v*)&Ah[lrow][ko];
        s8v al = *(const s8v*)&Al[lrow][ko];
        acc0 = __builtin_amdgcn_mfma_f32_16x16x32_bf16(ah, bh, acc0, 0, 0, 0);
        acc0 = __builtin_amdgcn_mfma_f32_16x16x32_bf16(ah, bl, acc0, 0, 0, 0);
        acc0 = __builtin_amdgcn_mfma_f32_16x16x32_bf16(al, bh, acc0, 0, 0, 0);
      }
      {
        s8v ah = *(const s8v*)&Ah[16 + lrow][ko];
        s8v al = *(const s8v*)&Al[16 + lrow][ko];
        acc1 = __builtin_amdgcn_mfma_f32_16x16x32_bf16(ah, bh, acc1, 0, 0, 0);
        acc1 = __builtin_amdgcn_mfma_f32_16x16x32_bf16(ah, bl, acc1, 0, 0, 0);
        acc1 = __builtin_amdgcn_mfma_f32_16x16x32_bf16(al, bh, acc1, 0, 0, 0);
      }
    }
    __syncthreads();
  }

  if (mode == 4) {
    float a0 = rs0, a1 = rs1;
#pragma unroll
    for (int off = 8; off; off >>= 1) {
      a0 += __shfl_xor(a0, off, 16);
      a1 += __shfl_xor(a1, off, 16);
    }
    if ((t & 15) == 0) { rowsuml[t >> 4] = a0; rowsuml[16 + (t >> 4)] = a1; }
    __syncthreads();
  }

  // epilogue: C/D layout col=lane&15, row=(lane>>4)*4+reg (m89-verified)
  int col = colbase + w4 * 16 + lrow;
  int qrow = ((t & 63) >> 4) * 4;
  if (d.Cth) {
    // producer GEMMs (bias=0, act=0): write C^T bf16 hi/lo planes
    size_t cb = (size_t)col * d.Ckp + rowbase + qrow;
#pragma unroll
    for (int m = 0; m < 2; ++m) {
      u16 hh[4], ll[4];
#pragma unroll
      for (int q = 0; q < 4; ++q) split_bf16(m ? acc1[q] : acc0[q], hh[q], ll[q]);
      *(short4*)&d.Cth[cb + m * 16] = make_short4((short)hh[0], (short)hh[1], (short)hh[2], (short)hh[3]);
      *(short4*)&d.Ctl[cb + m * 16] = make_short4((short)ll[0], (short)ll[1], (short)ll[2], (short)ll[3]);
    }
  }
  if (d.C) {
    float bvs = d.bias ? d.bias[col] : 0.f;
#pragma unroll
    for (int m = 0; m < 2; ++m) {
#pragma unroll
      for (int q = 0; q < 4; ++q) {
        int lr = m * 16 + qrow + q;
        int row = rowbase + lr;
        if (row >= M) continue;
        float o = (m ? acc1[q] : acc0[q]) + bvs;
        if (d.act) o = fmaxf(o, 0.f);
        if (mode == 4) o *= (1.f / rowsuml[lr]);
        d.C[(size_t)row * Nn + col] = o;
      }
    }
  }
}

// expwsc[j] = exp(V[j] . u), u = W1 @ a_std1
__device__ void wsc_body(char* smem, const float* W1, const float* a_std1,
                         const float* V, float* expwsc, int grp) {
  float* asl = (float*)smem;
  float* ul  = asl + 256;
  int t = threadIdx.x;
  asl[t] = a_std1[t];
  __syncthreads();
  {
    float s = 0.f;
    const float* wr = W1 + t * 256;
    for (int h = 0; h < 256; h += 4) {
      float4 w4 = *(const float4*)&wr[h];
      float4 a4 = *(const float4*)&asl[h];
      s += w4.x * a4.x + w4.y * a4.y + w4.z * a4.z + w4.w * a4.w;
    }
    ul[t] = s;
  }
  __syncthreads();
  int wave = t >> 6, lane = t & 63;
  float4 u4 = *(const float4*)&ul[lane * 4];
  int j0 = grp * 128;
  for (int j = j0 + wave; j < j0 + 128; j += 4) {
    float4 v4 = *(const float4*)&V[j * 256 + lane * 4];
    float s = v4.x * u4.x + v4.y * u4.y + v4.z * u4.z + v4.w * u4.w;
#pragma unroll
    for (int off = 32; off; off >>= 1) s += __shfl_xor(s, off, 64);
    if (lane == 0) expwsc[j] = __expf(s);
  }
}

struct GD7 {
  GD d[7];
  const float *tw2, *cw2, *ce_w2, *a_c0, *a_c1;
  u16 *tw2h, *tw2l, *cw2h, *cw2l, *wfh, *wfl;
  float* wclg;
  unsigned* cnts;
};

// launch-1 spare blocks: one-time converters (te_w2/co_w2 -> transposed
// bf16 planes), wcl GEMV, Wfused-plane tail zero, counter zero.
__device__ void conv_body(char* smem, int bx, const GD7& a) {
  float (*Ls)[66] = (float(*)[66])smem;
  int t = threadIdx.x;
  const float* src = (bx < 2) ? a.tw2 : a.cw2;
  u16* dh = (bx < 2) ? a.tw2h : a.cw2h;
  u16* dl = (bx < 2) ? a.tw2l : a.cw2l;
  int k0 = (bx & 1) * 128;
  for (int kt = 0; kt < 2; ++kt) {
    int k00 = k0 + kt * 64;
#pragma unroll
    for (int j = 0; j < 4; ++j) {
      int idx = t + j * 256;
      int r = idx >> 4, c = (idx & 15) * 4;
      *(float4*)&Ls[r][c] = *(const float4*)&src[(k00 + r) * 64 + c];
    }
    __syncthreads();
#pragma unroll
    for (int j = 0; j < 4; ++j) {
      int idx = t + j * 256;
      int n = idx >> 4, kk = (idx & 15) * 4;
      u16 hh[4], ll[4];
#pragma unroll
      for (int e = 0; e < 4; ++e) split_bf16(Ls[kk + e][n], hh[e], ll[e]);
      *(short4*)&dh[n * 256 + k00 + kk] = make_short4((short)hh[0], (short)hh[1], (short)hh[2], (short)hh[3]);
      *(short4*)&dl[n * 256 + k00 + kk] = make_short4((short)ll[0], (short)ll[1], (short)ll[2], (short)ll[3]);
    }
    __syncthreads();
  }
  if (bx == 3) {
    if (t < 36) a.cnts[t] = 0u;
    // wclg = ce_w2 @ (a_c0 + a_c1), block-invariant for all pair tiles
    float s = 0.f;
    const float* w2r = a.ce_w2 + t * 64;
    for (int h = 0; h < 64; ++h) s += w2r[h] * (a.a_c0[h] + a.a_c1[h]);
    a.wclg[t] = s;
    // zero Wfused plane rows k in [416,448) (never written by z=5)
    int n = t;
    for (int kk = 416; kk < 448; kk += 4) {
      *(short4*)&a.wfh[n * 448 + kk] = make_short4(0, 0, 0, 0);
      *(short4*)&a.wfl[n * 448 + kk] = make_short4(0, 0, 0, 0);
    }
  }
}

__global__ __launch_bounds__(256) void gemm7_k(GD7 ds) {
  __shared__ __align__(16) char smem[GEMM_SMEM];
  int z = blockIdx.z;
  if (z == 6) {
    if (blockIdx.y == 0) { wsc_body(smem, ds.d[6].A, ds.d[6].A2, ds.d[6].A3, ds.d[6].C, blockIdx.x); return; }
    if (blockIdx.y == 1) { conv_body(smem, blockIdx.x, ds); return; }
    return;
  }
  gemm_body(smem, ds.d[z], blockIdx.x, blockIdx.y);
}

// ============================ pair body =================================
__device__ void pair_body(char* smem,
    const float* __restrict__ P, const float* __restrict__ Q,
    const float* __restrict__ b1, const float* __restrict__ ce_w2,
    const float* __restrict__ wclg,
    float* __restrict__ mpart, float* __restrict__ dpart,
    float* __restrict__ spart, int byy, int bxx) {
  float* Pl  = (float*)smem;        // 16*260
  float* Ql  = Pl + 16 * 260;       // 16*260
  float* el  = Ql + 16 * 260;       // 16*20
  float* wcl = el + 16 * 20;        // 256
  float* red = wcl + 256;           // 256
  float* sk  = red + 256;           // 256
  float* sbl = sk + 256;            // 256
  int t = threadIdx.x;

  wcl[t] = wclg[t];
  int i0 = byy * 16, j0 = bxx * 16;
  for (int e = t; e < 1024; e += 256) {
    int r = e >> 6, c4 = (e & 63) * 4;
    float4 bb = *(const float4*)&b1[c4];
    float4 pv = *(const float4*)&P[(i0 + r) * 256 + c4];
    pv.x += bb.x; pv.y += bb.y; pv.z += bb.z; pv.w += bb.w;
    *(float4*)&Pl[r * 260 + c4] = pv;
    *(float4*)&Ql[r * 260 + c4] = *(const float4*)&Q[(j0 + r) * 256 + c4];
  }
  __syncthreads();

  int a = t >> 4, b = t & 15;
  const float* pr = &Pl[a * 260];
  const float* qr = &Ql[b * 260];
  float4 c4a = make_float4(0.f, 0.f, 0.f, 0.f);
#pragma unroll 8
  for (int k4 = 0; k4 < 64; ++k4) {
    float4 w = *(const float4*)&wcl[k4 * 4];
    float4 p = *(const float4*)&pr[k4 * 4];
    float4 q = *(const float4*)&qr[k4 * 4];
    c4a.x += fmaxf(p.x + q.x, 0.f) * w.x;
    c4a.y += fmaxf(p.y + q.y, 0.f) * w.y;
    c4a.z += fmaxf(p.z + q.z, 0.f) * w.z;
    c4a.w += fmaxf(p.w + q.w, 0.f) * w.w;
  }
  float s = c4a.x + c4a.y + c4a.z + c4a.w;
  if (i0 + a == j0 + b) s = -INFINITY;
  // wave-level max/sum reductions (R2: replaces 16-barrier LDS trees)
  float wm = s;
#pragma unroll
  for (int off = 32; off; off >>= 1) wm = fmaxf(wm, __shfl_xor(wm, off, 64));
  if ((t & 63) == 0) red[t >> 6] = wm;
  __syncthreads();
  float mb = fmaxf(fmaxf(red[0], red[1]), fmaxf(red[2], red[3]));
  float e = __expf(s - mb);
  el[a * 20 + b] = e;
  float ws2 = e;
#pragma unroll
  for (int off = 32; off; off >>= 1) ws2 += __shfl_xor(ws2, off, 64);
  if ((t & 63) == 0) red[8 + (t >> 6)] = ws2;
  __syncthreads();
  float db = red[8] + red[9] + red[10] + red[11];

  // pass 2: thread t owns feature k=t (static register indexing ONLY)
  float qv[16];
#pragma unroll
  for (int j = 0; j < 16; ++j) qv[j] = Ql[j * 260 + t];
  float rk = 0.f;
#pragma unroll 4
  for (int i = 0; i < 16; ++i) {
    float pv = Pl[i * 260 + t];
    const float* erow = &el[i * 20];
#pragma unroll
    for (int j4 = 0; j4 < 4; ++j4) {
      float4 e4 = *(const float4*)&erow[j4 * 4];
      rk += e4.x * fmaxf(pv + qv[j4 * 4 + 0], 0.f);
      rk += e4.y * fmaxf(pv + qv[j4 * 4 + 1], 0.f);
      rk += e4.z * fmaxf(pv + qv[j4 * 4 + 2], 0.f);
      rk += e4.w * fmaxf(pv + qv[j4 * 4 + 3], 0.f);
    }
  }
  sk[t] = rk;
  __syncthreads();
  {
    int h = t & 63, q = t >> 6;
    float s2 = 0.f;
    for (int k = q * 64; k < q * 64 + 64; ++k) s2 += sk[k] * ce_w2[k * 64 + h];
    sbl[q * 64 + h] = s2;
  }
  __syncthreads();
  int blk = byy * 32 + bxx;
  if (t < 64) spart[blk * 64 + t] = sbl[t] + sbl[64 + t] + sbl[128 + t] + sbl[192 + t];
  if (t == 0) { mpart[blk] = mb; dpart[blk] = db; }
}

// ============================== mega kernel ===============================
struct MegaArgs {
  const float *P, *Q, *b1, *ce_w2, *wclg;
  float *mpart, *dpart, *spart;
  const float *ce_b2; float *H2row;
  const float *tf; float *H3;
  const float *cf4; float *h4vec;
  unsigned* cnts;
  GD gH1, gTf, gCf;
};

// 256-thread finalize jobs (formerly mini_k), run by last-done producers.
__device__ void mini_job(char* smem, int job, const MegaArgs& a) {
  float* Ash = (float*)smem;           // 256
  float* Bsh = Ash + 256;              // 1024
  int t = threadIdx.x;
  int h = t & 63, g = t >> 6;
  if (job == 0) {
    float mv[4];
    float m0 = -INFINITY;
#pragma unroll
    for (int i = 0; i < 4; ++i) { mv[i] = a.mpart[t + i * 256]; m0 = fmaxf(m0, mv[i]); }
    Ash[t] = m0; __syncthreads();
    for (int s = 128; s; s >>= 1) { if (t < s) Ash[t] = fmaxf(Ash[t], Ash[t + s]); __syncthreads(); }
    float M = Ash[0]; __syncthreads();
    float d0 = 0.f;
#pragma unroll
    for (int i = 0; i < 4; ++i) {
      float e = __expf(mv[i] - M);
      Bsh[t + i * 256] = e;
      d0 += e * a.dpart[t + i * 256];
    }
    Ash[t] = d0; __syncthreads();
    for (int s = 128; s; s >>= 1) { if (t < s) Ash[t] += Ash[t + s]; __syncthreads(); }
    float D = Ash[0]; __syncthreads();
    float s2 = 0.f;
    for (int b2 = g * 256; b2 < g * 256 + 256; ++b2) s2 += Bsh[b2] * a.spart[b2 * 64 + h];
    Ash[t] = s2; __syncthreads();
    if (g == 0) {
      float r = Ash[h] + Ash[64 + h] + Ash[128 + h] + Ash[192 + h];
      a.H2row[h] = r / D + a.ce_b2[h];
    }
  } else if (job == 1) {
    // H3[i] = mean(tf[0..i])
    float run = 0.f;
    for (int r = 0; r < 128; ++r) run += a.tf[(g * 128 + r) * 64 + h];
    Ash[g * 64 + h] = run; __syncthreads();
    float off = 0.f;
    for (int gg = 0; gg < g; ++gg) off += Ash[gg * 64 + h];
    float run2 = off;
    for (int r = 0; r < 128; ++r) {
      int i = g * 128 + r;
      run2 += a.tf[i * 64 + h];
      a.H3[i * 64 + h] = run2 / (float)(i + 1);
    }
  } else {
    float s = 0.f;
    for (int r = 0; r < 128; ++r) s += a.cf4[(g * 128 + r) * 64 + h];
    Ash[g * 64 + h] = s; __syncthreads();
    if (g == 0) a.h4vec[h] = Ash[h] + Ash[64 + h] + Ash[128 + h] + Ash[192 + h];
  }
}

__global__ __launch_bounds__(256) void mega_k(MegaArgs a) {
  __shared__ __align__(16) char smem[MEGA_SMEM];
  int b = blockIdx.x;
  if (b < 64) {
    gemm_body(smem, a.gH1, b & 3, b >> 2);
  } else if (b < 96) {
    int isTf = (b < 80);
    gemm_body(smem, isTf ? a.gTf : a.gCf, 0, isTf ? (b - 64) : (b - 80));
    __syncthreads();
    __threadfence();
    __shared__ unsigned po;
    if (threadIdx.x == 0) po = atomicAdd(&a.cnts[isTf ? 17 : 18], 1u);
    __syncthreads();
    if (po == 15u) { __threadfence(); mini_job(smem, isTf ? 1 : 2, a); }
  } else {
    int p = b - 96;
    pair_body(smem, a.P, a.Q, a.b1, a.ce_w2, a.wclg,
              a.mpart, a.dpart, a.spart, p >> 5, p & 31);
    __syncthreads();
    __threadfence();
    __shared__ unsigned po;
    if (threadIdx.x == 0) {
      unsigned fin = 0xffffffffu;
      unsigned g1 = atomicAdd(&a.cnts[20 + (p >> 6)], 1u);  // 16 groups of 64
      if (g1 == 63u) fin = atomicAdd(&a.cnts[16], 1u);
      po = fin;
    }
    __syncthreads();
    if (po == 15u) { __threadfence(); mini_job(smem, 0, a); }
  }
}

// ================= final GEMM (T2) with fused layernorm+elu ===============
__global__ __launch_bounds__(256) void gemm_ln_k(GD d, const float* __restrict__ lng,
                                                 const float* __restrict__ lnb,
                                                 float* __restrict__ out, unsigned* cnts) {
  __shared__ __align__(16) char smem[GEMM_SMEM];
  gemm_body(smem, d, blockIdx.x, blockIdx.y);
  __syncthreads();
  __threadfence();
  __shared__ unsigned po;
  if (threadIdx.x == 0) po = atomicAdd(&cnts[blockIdx.y], 1u);
  __syncthreads();
  if (po == 3u) {
    __threadfence();
    int t = threadIdx.x, lane = t & 63, w = t >> 6;
    const float* T2 = d.C;
    for (int r8 = 0; r8 < 8; ++r8) {
      int row = blockIdx.y * 32 + w * 8 + r8;
      float4 x = *(const float4*)&T2[row * 256 + lane * 4];
      float s = x.x + x.y + x.z + x.w;
#pragma unroll
      for (int off = 32; off; off >>= 1) s += __shfl_xor(s, off, 64);
      float mu = s * (1.f / 256.f);
      float4 dv = make_float4(x.x - mu, x.y - mu, x.z - mu, x.w - mu);
      float s2 = dv.x * dv.x + dv.y * dv.y + dv.z * dv.z + dv.w * dv.w;
#pragma unroll
      for (int off = 32; off; off >>= 1) s2 += __shfl_xor(s2, off, 64);
      float rstd = 1.f / sqrtf(s2 * (1.f / 256.f) + EPSV);
      float4 gg = *(const float4*)&lng[lane * 4];
      float4 bb = *(const float4*)&lnb[lane * 4];
      float4 y;
      y.x = dv.x * rstd * gg.x + bb.x;
      y.y = dv.y * rstd * gg.y + bb.y;
      y.z = dv.z * rstd * gg.z + bb.z;
      y.w = dv.w * rstd * gg.w + bb.w;
      y.x = (y.x > 0.f) ? y.x : (expf(y.x) - 1.f);
      y.y = (y.y > 0.f) ? y.y : (expf(y.y) - 1.f);
      y.z = (y.z > 0.f) ? y.z : (expf(y.z) - 1.f);
      y.w = (y.w > 0.f) ? y.w : (expf(y.w) - 1.f);
      *(float4*)&out[row * 256 + lane * 4] = y;
    }
  }
}

static GD mkgd(const float* A, const float* A2, const float* A3, const float* A4,
               const int* I, const float* B, const float* bias, float* C,
               int M, int K, int Nn, int mode, int act) {
  GD g{A, A2, A3, A4, I, B, bias, C, 0, 0, 0, 0, 0, 0, M, K, Nn, mode, act};
  return g;
}

extern "C" void kernel_launch(void* const* d_in, const int* in_sizes, int n_in,
                              void* d_out, int out_size, void* d_ws, size_t ws_size,
                              hipStream_t stream) {
  const float* V      = (const float*)d_in[0];
  const int*   adj    = (const int*)  d_in[1];
  const float* ph     = (const float*)d_in[2];
  const float* W1     = (const float*)d_in[3];
  const float* a_std1 = (const float*)d_in[5];
  const float* ce_w1  = (const float*)d_in[6];
  const float* ce_b1  = (const float*)d_in[7];
  const float* ce_w2  = (const float*)d_in[8];
  const float* ce_b2  = (const float*)d_in[9];
  const float* a_c0   = (const float*)d_in[10];
  const float* a_c1   = (const float*)d_in[11];
  const float* te_w1  = (const float*)d_in[12];
  const float* te_b1  = (const float*)d_in[13];
  const float* te_w2  = (const float*)d_in[14];
  const float* te_b2  = (const float*)d_in[15];
  const float* co_w1  = (const float*)d_in[18];
  const float* co_b1  = (const float*)d_in[19];
  const float* co_w2  = (const float*)d_in[20];
  const float* co_b2  = (const float*)d_in[21];
  const float* W2     = (const float*)d_in[24];
  const float* Wo     = (const float*)d_in[25];
  const float* bo     = (const float*)d_in[26];
  const float* ln_g   = (const float*)d_in[27];
  const float* ln_b   = (const float*)d_in[28];
  float* out = (float*)d_out;

  float* ws = (float*)d_ws;
  size_t off = 0;
  auto alloc = [&](size_t n) { float* p = ws + off; off += (n + 15) & ~(size_t)15; return p; };

  float* Pb     = alloc(512 * 256);
  float* Qb     = alloc(512 * 256);
  float* tfh    = alloc(512 * 256);
  float* cf4h   = alloc(512 * 256);
  float* H1     = alloc(512 * 256);
  float* T2     = alloc(512 * 256);
  float* tf     = alloc(512 * 64);
  float* cf4    = alloc(512 * 64);
  float* H3     = alloc(512 * 64);
  float* spart  = alloc(1024 * 64);
  float* mpart  = alloc(1024);
  float* dpart  = alloc(1024);
  float* expwsc = alloc(512);
  float* H2row  = alloc(64);
  float* h4vec  = alloc(64);
  // bf16 hi/lo planes (u16 counts / 2 = float counts)
  u16* Wh1t_h = (u16*)alloc(65536);   // [256][512]
  u16* Wh1t_l = (u16*)alloc(65536);
  u16* Wf_h   = (u16*)alloc(57344);   // [256][448]
  u16* Wf_l   = (u16*)alloc(57344);
  u16* tw2h   = (u16*)alloc(8192);    // [64][256]
  u16* tw2l   = (u16*)alloc(8192);
  u16* cw2h   = (u16*)alloc(8192);
  u16* cw2l   = (u16*)alloc(8192);
  float* wclg = alloc(256);
  unsigned* cnts = (unsigned*)alloc(64);
  (void)ws_size; (void)in_sizes; (void)n_in; (void)out_size;

  // ---- launch 1: six leading GEMMs + wsc slice + converters ----
  GD7 sA;
  sA.d[0] = mkgd(V, 0, 0, 0, 0, W1, 0, 0, 512, 256, 256, 0, 0);
  sA.d[0].Cth = Wh1t_h; sA.d[0].Ctl = Wh1t_l; sA.d[0].Ckp = 512;
  sA.d[1] = mkgd(V, 0, 0, 0, 0, ce_w1, 0, Pb, 512, 256, 256, 0, 0);
  sA.d[2] = mkgd(V, 0, 0, 0, 0, ce_w1 + 256 * 256, 0, Qb, 512, 256, 256, 0, 0);
  sA.d[3] = mkgd(V, ph, 0, 0, 0, te_w1, te_b1, tfh, 512, 512, 256, 1, 1);
  sA.d[4] = mkgd(V, 0, 0, 0, adj, co_w1, co_b1, cf4h, 512, 768, 256, 2, 1);
  sA.d[5] = mkgd(W2, 0, 0, 0, 0, Wo, 0, 0, 385, 256, 256, 0, 0);
  sA.d[5].Cth = Wf_h; sA.d[5].Ctl = Wf_l; sA.d[5].Ckp = 448;
  sA.d[6] = mkgd(W1, a_std1, V, 0, 0, 0, 0, expwsc, 512, 256, 1, 6, 0);
  sA.tw2 = te_w2; sA.cw2 = co_w2; sA.ce_w2 = ce_w2; sA.a_c0 = a_c0; sA.a_c1 = a_c1;
  sA.tw2h = tw2h; sA.tw2l = tw2l; sA.cw2h = cw2h; sA.cw2l = cw2l;
  sA.wfh = Wf_h; sA.wfl = Wf_l; sA.wclg = wclg; sA.cnts = cnts;
  gemm7_k<<<dim3(4, 16, 7), 256, 0, stream>>>(sA);

  // ---- launch 2: H1 + tf + cf4 gemms + 1024 pair tiles + fused finalize ----
  MegaArgs ma;
  ma.P = Pb; ma.Q = Qb; ma.b1 = ce_b1; ma.ce_w2 = ce_w2; ma.wclg = wclg;
  ma.mpart = mpart; ma.dpart = dpart; ma.spart = spart;
  ma.ce_b2 = ce_b2; ma.H2row = H2row;
  ma.tf = tf; ma.H3 = H3; ma.cf4 = cf4; ma.h4vec = h4vec;
  ma.cnts = cnts;
  ma.gH1 = mkgd(0, expwsc, 0, 0, adj, 0, 0, H1, 512, 512, 256, 4, 0);
  ma.gH1.Bth = Wh1t_h; ma.gH1.Btl = Wh1t_l; ma.gH1.Bkp = 512;
  ma.gTf = mkgd(tfh, 0, 0, 0, 0, 0, te_b2, tf, 512, 256, 64, 0, 0);
  ma.gTf.Bth = tw2h; ma.gTf.Btl = tw2l; ma.gTf.Bkp = 256;
  ma.gCf = mkgd(cf4h, 0, 0, 0, 0, 0, co_b2, cf4, 512, 256, 64, 0, 0);
  ma.gCf.Bth = cw2h; ma.gCf.Btl = cw2l; ma.gCf.Bkp = 256;
  mega_k<<<1120, 256, 0, stream>>>(ma);

  // ---- launch 3: T2 = virtual-Hc @ Wfused + bo, fused layernorm+elu ----
  GD gF = mkgd(H1, H2row, H3, h4vec, 0, 0, bo, T2, 512, 385, 256, 3, 0);
  gF.Bth = Wf_h; gF.Btl = Wf_l; gF.Bkp = 448;
  gemm_ln_k<<<dim3(4, 16), 256, 0, stream>>>(gF, ln_g, ln_b, out, cnts);
}

// Round 3
// 189.224 us; speedup vs baseline: 1.7202x; 1.7202x over previous
//
#include <hip/hip_runtime.h>
#include <math.h>

#define NN 512
#define HD 64
#define EPSV 1e-5f

typedef unsigned short u16;
typedef short s4v __attribute__((ext_vector_type(4)));
typedef short s8v __attribute__((ext_vector_type(8)));
typedef float f4v __attribute__((ext_vector_type(4)));

// ======================= multi-mode pipelined GEMM ========================
// 32(M) x 64(N) tile, 256 threads, BK=64, split-bf16 3-term MFMA
// (A*B ~= Ahi*Bhi + Ahi*Blo + Alo*Bhi, rel err ~2^-16).
// R3: back to the 5-launch skeleton (R2's per-block __threadfence = per-XCD
// L2 writeback/invalidate x1120 blocks -> latency crawl, 173us mega_k).
// Kept from R2: pre-split transposed bf16 B-planes (producers write them
// in epilogues; consumers stage B as pure 16B copies), wclg hoist,
// wave-level reductions in pair_body.
struct GD {
  const float *A, *A2, *A3, *A4;
  const int* I;
  const float *B, *bias;
  float* C;
  const u16 *Bth, *Btl;   // pre-split transposed B planes [n][Bkp]
  u16 *Cth, *Ctl;         // optional epilogue: write C^T planes [col][Ckp]
  int Bkp, Ckp;
  int M, K, Nn, mode, act;
};

// LDS: Ah 4608 + Al 4608 + Bh 8704 + Bl 8704 + extra 2176 = 28800
#define GEMM_SMEM 28800
#define MEGA_SMEM 38656

__device__ __forceinline__ void split_bf16(float x, u16& h, u16& l) {
  unsigned xb = __float_as_uint(x);
  float hf = __uint_as_float(xb & 0xffff0000u);
  h = (u16)(xb >> 16);
  l = (u16)(__float_as_uint(x - hf) >> 16);
}

__device__ __forceinline__ void gemm_body(char* smem, const GD& d, int bx, int by) {
  u16 (*Ah)[72] = (u16(*)[72])smem;
  u16 (*Al)[72] = (u16(*)[72])(smem + 4608);
  u16 (*Bh)[68] = (u16(*)[68])(smem + 9216);
  u16 (*Bl)[68] = (u16(*)[68])(smem + 9216 + 8704);
  char* extra = smem + 26624;
  int* nbl = (int*)extra;                 // mode 2: 32 rows x {n0,n1,valid}
  float* wscl = (float*)extra;            // mode 4: exp(wsc) (512)
  float* rowsuml = wscl + 512;            // mode 4: 32

  const int t = threadIdx.x;
  const int rowbase = by * 32, colbase = bx * 64;
  const int K = d.K, Nn = d.Nn, mode = d.mode, M = d.M;
  if (rowbase >= M) return;

  if (mode == 2) {
    int wave = t >> 6, lane = t & 63;
    for (int rr = wave; rr < 32; rr += 4) {
      int row = rowbase + rr;
      int n0 = -1, n1 = -1, cnt = 0;
      for (int c = 0; c < 8; ++c) {
        unsigned long long mm = __ballot(d.I[row * NN + c * 64 + lane] != 0);
        cnt += (int)__popcll(mm);
        if (n0 < 0 && mm) { n0 = c * 64 + (int)__builtin_ctzll(mm); mm &= mm - 1; }
        if (n1 < 0 && mm) { n1 = c * 64 + (int)__builtin_ctzll(mm); }
      }
      if (lane == 0) { nbl[rr * 3] = n0; nbl[rr * 3 + 1] = n1; nbl[rr * 3 + 2] = (cnt >= 2); }
    }
    __syncthreads();
  } else if (mode == 4) {
    wscl[t] = d.A2[t];
    wscl[256 + t] = d.A2[256 + t];
    __syncthreads();
  }

  float4 aR[2], bR[4];
  s8v bp[4];                    // plane path: [0..1]=hi, [2..3]=lo
  float rs0 = 0.f, rs1 = 0.f;   // mode-4 row sums

  auto loadA = [&](int k0) {
#pragma unroll
    for (int j = 0; j < 2; ++j) {
      int idx = t + j * 256;
      int r = idx >> 4, c0 = (idx & 15) * 4;
      int row = rowbase + r, gk = k0 + c0;
      float4 v4 = make_float4(0.f, 0.f, 0.f, 0.f);
      if (mode == 0) {
        if (row < M && gk < K) v4 = *(const float4*)&d.A[(size_t)row * K + gk];
      } else if (mode == 1) {
        if (gk < 256) v4 = *(const float4*)&d.A[row * 256 + gk];
        else v4 = *(const float4*)&d.A2[row * 256 + gk - 256];
      } else if (mode == 2) {
        int seg = gk >> 8;
        int src = (seg == 0) ? row : (nbl[r * 3 + 2] ? nbl[r * 3 + seg - 1] : -1);
        if (src >= 0) v4 = *(const float4*)&d.A[src * 256 + (gk & 255)];
      } else if (mode == 3) {
        if (gk + 3 < 256) v4 = *(const float4*)&d.A[row * 256 + gk];
        else if (gk >= 256 && gk + 3 < 320) v4 = *(const float4*)&d.A2[gk - 256];
        else if (gk >= 320 && gk + 3 < 384) v4 = *(const float4*)&d.A3[row * 64 + gk - 320];
        else if (gk == 384) v4.x = (row < 64) ? d.A4[row] : 0.f;
      } else {  // mode 4
        int4 a4 = *(const int4*)&d.I[row * NN + gk];
        v4.x = a4.x ? wscl[gk + 0] : 0.f;
        v4.y = a4.y ? wscl[gk + 1] : 0.f;
        v4.z = a4.z ? wscl[gk + 2] : 0.f;
        v4.w = a4.w ? wscl[gk + 3] : 0.f;
        float ss = v4.x + v4.y + v4.z + v4.w;
        if (j == 0) rs0 += ss; else rs1 += ss;
      }
      aR[j] = v4;
    }
  };
  auto loadB = [&](int k0) {
    if (d.Bth) {
#pragma unroll
      for (int j = 0; j < 2; ++j) {
        int idx = t + j * 256;
        int n = idx >> 3, kb = (idx & 7) * 8;
        size_t base = (size_t)(colbase + n) * d.Bkp + k0 + kb;
        bp[j] = *(const s8v*)&d.Bth[base];
        bp[2 + j] = *(const s8v*)&d.Btl[base];
      }
    } else {
#pragma unroll
      for (int j = 0; j < 4; ++j) {
        int idx = t + j * 256;
        int r = idx >> 4, c0 = (idx & 15) * 4;
        int gk = k0 + r;
        float4 v4 = make_float4(0.f, 0.f, 0.f, 0.f);
        if (gk < K) v4 = *(const float4*)&d.B[(size_t)gk * Nn + colbase + c0];
        bR[j] = v4;
      }
    }
  };
  auto stos = [&]() {
#pragma unroll
    for (int j = 0; j < 2; ++j) {
      int idx = t + j * 256;
      int r = idx >> 4, c0 = (idx & 15) * 4;
      float v[4] = {aR[j].x, aR[j].y, aR[j].z, aR[j].w};
      u16 h[4], l[4];
#pragma unroll
      for (int e = 0; e < 4; ++e) split_bf16(v[e], h[e], l[e]);
      *(short4*)&Ah[r][c0] = make_short4((short)h[0], (short)h[1], (short)h[2], (short)h[3]);
      *(short4*)&Al[r][c0] = make_short4((short)l[0], (short)l[1], (short)l[2], (short)l[3]);
    }
    if (d.Bth) {
#pragma unroll
      for (int j = 0; j < 2; ++j) {
        int idx = t + j * 256;
        int n = idx >> 3, kb = (idx & 7) * 8;
        *(s8v*)&Bh[n][kb] = bp[j];
        *(s8v*)&Bl[n][kb] = bp[2 + j];
      }
    } else {
#pragma unroll
      for (int j = 0; j < 4; ++j) {
        int idx = t + j * 256;
        int r = idx >> 4, c0 = (idx & 15) * 4;
        float v[4] = {bR[j].x, bR[j].y, bR[j].z, bR[j].w};
#pragma unroll
        for (int e = 0; e < 4; ++e) {
          u16 h, l;
          split_bf16(v[e], h, l);
          Bh[c0 + e][r] = h;
          Bl[c0 + e][r] = l;
        }
      }
    }
  };

  f4v acc0 = {0.f, 0.f, 0.f, 0.f};
  f4v acc1 = {0.f, 0.f, 0.f, 0.f};

  const int w4 = t >> 6;
  const int lrow = t & 15;
  const int lk = ((t & 63) >> 4) * 8;

  int iters = (K + 63) >> 6;
  loadA(0); loadB(0);
  for (int it = 0; it < iters; ++it) {
    stos();
    __syncthreads();
    if (it + 1 < iters) { loadA((it + 1) << 6); loadB((it + 1) << 6); }
    const u16* bhrow = Bh[w4 * 16 + lrow];
    const u16* blrow = Bl[w4 * 16 + lrow];
#pragma unroll
    for (int ks = 0; ks < 2; ++ks) {
      int ko = ks * 32 + lk;
      s4v bh_0 = *(const s4v*)&bhrow[ko];
      s4v bh_1 = *(const s4v*)&bhrow[ko + 4];
      s4v bl_0 = *(const s4v*)&blrow[ko];
      s4v bl_1 = *(const s4v*)&blrow[ko + 4];
      s8v bh = __builtin_shufflevector(bh_0, bh_1, 0, 1, 2, 3, 4, 5, 6, 7);
      s8v bl = __builtin_shufflevector(bl_0, bl_1, 0, 1, 2, 3, 4, 5, 6, 7);
      {
        s8v ah = *(const s8v*)&Ah[lrow][ko];
        s8v al = *(const s8v*)&Al[lrow][ko];
        acc0 = __builtin_amdgcn_mfma_f32_16x16x32_bf16(ah, bh, acc0, 0, 0, 0);
        acc0 = __builtin_amdgcn_mfma_f32_16x16x32_bf16(ah, bl, acc0, 0, 0, 0);
        acc0 = __builtin_amdgcn_mfma_f32_16x16x32_bf16(al, bh, acc0, 0, 0, 0);
      }
      {
        s8v ah = *(const s8v*)&Ah[16 + lrow][ko];
        s8v al = *(const s8v*)&Al[16 + lrow][ko];
        acc1 = __builtin_amdgcn_mfma_f32_16x16x32_bf16(ah, bh, acc1, 0, 0, 0);
        acc1 = __builtin_amdgcn_mfma_f32_16x16x32_bf16(ah, bl, acc1, 0, 0, 0);
        acc1 = __builtin_amdgcn_mfma_f32_16x16x32_bf16(al, bh, acc1, 0, 0, 0);
      }
    }
    __syncthreads();
  }

  if (mode == 4) {
    float a0 = rs0, a1 = rs1;
#pragma unroll
    for (int off = 8; off; off >>= 1) {
      a0 += __shfl_xor(a0, off, 16);
      a1 += __shfl_xor(a1, off, 16);
    }
    if ((t & 15) == 0) { rowsuml[t >> 4] = a0; rowsuml[16 + (t >> 4)] = a1; }
    __syncthreads();
  }

  // epilogue: C/D layout col=lane&15, row=(lane>>4)*4+reg (m89-verified)
  int col = colbase + w4 * 16 + lrow;
  int qrow = ((t & 63) >> 4) * 4;
  if (d.Cth) {
    // producer GEMMs (bias=0, act=0): write C^T bf16 hi/lo planes
    size_t cb = (size_t)col * d.Ckp + rowbase + qrow;
#pragma unroll
    for (int m = 0; m < 2; ++m) {
      u16 hh[4], ll[4];
#pragma unroll
      for (int q = 0; q < 4; ++q) split_bf16(m ? acc1[q] : acc0[q], hh[q], ll[q]);
      *(short4*)&d.Cth[cb + m * 16] = make_short4((short)hh[0], (short)hh[1], (short)hh[2], (short)hh[3]);
      *(short4*)&d.Ctl[cb + m * 16] = make_short4((short)ll[0], (short)ll[1], (short)ll[2], (short)ll[3]);
    }
  }
  if (d.C) {
    float bvs = d.bias ? d.bias[col] : 0.f;
#pragma unroll
    for (int m = 0; m < 2; ++m) {
#pragma unroll
      for (int q = 0; q < 4; ++q) {
        int lr = m * 16 + qrow + q;
        int row = rowbase + lr;
        if (row >= M) continue;
        float o = (m ? acc1[q] : acc0[q]) + bvs;
        if (d.act) o = fmaxf(o, 0.f);
        if (mode == 4) o *= (1.f / rowsuml[lr]);
        d.C[(size_t)row * Nn + col] = o;
      }
    }
  }
}

// expwsc[j] = exp(V[j] . u), u = W1 @ a_std1
__device__ void wsc_body(char* smem, const float* W1, const float* a_std1,
                         const float* V, float* expwsc, int grp) {
  float* asl = (float*)smem;
  float* ul  = asl + 256;
  int t = threadIdx.x;
  asl[t] = a_std1[t];
  __syncthreads();
  {
    float s = 0.f;
    const float* wr = W1 + t * 256;
    for (int h = 0; h < 256; h += 4) {
      float4 w4 = *(const float4*)&wr[h];
      float4 a4 = *(const float4*)&asl[h];
      s += w4.x * a4.x + w4.y * a4.y + w4.z * a4.z + w4.w * a4.w;
    }
    ul[t] = s;
  }
  __syncthreads();
  int wave = t >> 6, lane = t & 63;
  float4 u4 = *(const float4*)&ul[lane * 4];
  int j0 = grp * 128;
  for (int j = j0 + wave; j < j0 + 128; j += 4) {
    float4 v4 = *(const float4*)&V[j * 256 + lane * 4];
    float s = v4.x * u4.x + v4.y * u4.y + v4.z * u4.z + v4.w * u4.w;
#pragma unroll
    for (int off = 32; off; off >>= 1) s += __shfl_xor(s, off, 64);
    if (lane == 0) expwsc[j] = __expf(s);
  }
}

struct GD7 {
  GD d[7];
  const float *tw2, *cw2, *ce_w2, *a_c0, *a_c1;
  u16 *tw2h, *tw2l, *cw2h, *cw2l, *wfh, *wfl;
  float* wclg;
};

// launch-1 spare blocks: one-time converters (te_w2/co_w2 -> transposed
// bf16 planes), wcl GEMV, Wfused-plane tail zero.
__device__ void conv_body(char* smem, int bx, const GD7& a) {
  float (*Ls)[66] = (float(*)[66])smem;
  int t = threadIdx.x;
  const float* src = (bx < 2) ? a.tw2 : a.cw2;
  u16* dh = (bx < 2) ? a.tw2h : a.cw2h;
  u16* dl = (bx < 2) ? a.tw2l : a.cw2l;
  int k0 = (bx & 1) * 128;
  for (int kt = 0; kt < 2; ++kt) {
    int k00 = k0 + kt * 64;
#pragma unroll
    for (int j = 0; j < 4; ++j) {
      int idx = t + j * 256;
      int r = idx >> 4, c = (idx & 15) * 4;
      *(float4*)&Ls[r][c] = *(const float4*)&src[(k00 + r) * 64 + c];
    }
    __syncthreads();
#pragma unroll
    for (int j = 0; j < 4; ++j) {
      int idx = t + j * 256;
      int n = idx >> 4, kk = (idx & 15) * 4;
      u16 hh[4], ll[4];
#pragma unroll
      for (int e = 0; e < 4; ++e) split_bf16(Ls[kk + e][n], hh[e], ll[e]);
      *(short4*)&dh[n * 256 + k00 + kk] = make_short4((short)hh[0], (short)hh[1], (short)hh[2], (short)hh[3]);
      *(short4*)&dl[n * 256 + k00 + kk] = make_short4((short)ll[0], (short)ll[1], (short)ll[2], (short)ll[3]);
    }
    __syncthreads();
  }
  if (bx == 3) {
    // wclg = ce_w2 @ (a_c0 + a_c1), block-invariant for all pair tiles
    float s = 0.f;
    const float* w2r = a.ce_w2 + t * 64;
    for (int h = 0; h < 64; ++h) s += w2r[h] * (a.a_c0[h] + a.a_c1[h]);
    a.wclg[t] = s;
    // zero Wfused plane rows k in [416,448) (never written by z=5)
    int n = t;
    for (int kk = 416; kk < 448; kk += 4) {
      *(short4*)&a.wfh[n * 448 + kk] = make_short4(0, 0, 0, 0);
      *(short4*)&a.wfl[n * 448 + kk] = make_short4(0, 0, 0, 0);
    }
  }
}

__global__ __launch_bounds__(256) void gemm7_k(GD7 ds) {
  __shared__ __align__(16) char smem[GEMM_SMEM];
  int z = blockIdx.z;
  if (z == 6) {
    if (blockIdx.y == 0) { wsc_body(smem, ds.d[6].A, ds.d[6].A2, ds.d[6].A3, ds.d[6].C, blockIdx.x); return; }
    if (blockIdx.y == 1) { conv_body(smem, blockIdx.x, ds); return; }
    return;
  }
  gemm_body(smem, ds.d[z], blockIdx.x, blockIdx.y);
}
__global__ __launch_bounds__(256) void gemm1_k(GD d) {
  __shared__ __align__(16) char smem[GEMM_SMEM];
  gemm_body(smem, d, blockIdx.x, blockIdx.y);
}

// ============================ pair body =================================
__device__ void pair_body(char* smem,
    const float* __restrict__ P, const float* __restrict__ Q,
    const float* __restrict__ b1, const float* __restrict__ ce_w2,
    const float* __restrict__ wclg,
    float* __restrict__ mpart, float* __restrict__ dpart,
    float* __restrict__ spart, int byy, int bxx) {
  float* Pl  = (float*)smem;        // 16*260
  float* Ql  = Pl + 16 * 260;       // 16*260
  float* el  = Ql + 16 * 260;       // 16*20
  float* wcl = el + 16 * 20;        // 256
  float* red = wcl + 256;           // 256
  float* sk  = red + 256;           // 256
  float* sbl = sk + 256;            // 256
  int t = threadIdx.x;

  wcl[t] = wclg[t];
  int i0 = byy * 16, j0 = bxx * 16;
  for (int e = t; e < 1024; e += 256) {
    int r = e >> 6, c4 = (e & 63) * 4;
    float4 bb = *(const float4*)&b1[c4];
    float4 pv = *(const float4*)&P[(i0 + r) * 256 + c4];
    pv.x += bb.x; pv.y += bb.y; pv.z += bb.z; pv.w += bb.w;
    *(float4*)&Pl[r * 260 + c4] = pv;
    *(float4*)&Ql[r * 260 + c4] = *(const float4*)&Q[(j0 + r) * 256 + c4];
  }
  __syncthreads();

  int a = t >> 4, b = t & 15;
  const float* pr = &Pl[a * 260];
  const float* qr = &Ql[b * 260];
  float4 c4a = make_float4(0.f, 0.f, 0.f, 0.f);
#pragma unroll 8
  for (int k4 = 0; k4 < 64; ++k4) {
    float4 w = *(const float4*)&wcl[k4 * 4];
    float4 p = *(const float4*)&pr[k4 * 4];
    float4 q = *(const float4*)&qr[k4 * 4];
    c4a.x += fmaxf(p.x + q.x, 0.f) * w.x;
    c4a.y += fmaxf(p.y + q.y, 0.f) * w.y;
    c4a.z += fmaxf(p.z + q.z, 0.f) * w.z;
    c4a.w += fmaxf(p.w + q.w, 0.f) * w.w;
  }
  float s = c4a.x + c4a.y + c4a.z + c4a.w;
  if (i0 + a == j0 + b) s = -INFINITY;
  // wave-level max/sum reductions (replaces 16-barrier LDS trees)
  float wm = s;
#pragma unroll
  for (int off = 32; off; off >>= 1) wm = fmaxf(wm, __shfl_xor(wm, off, 64));
  if ((t & 63) == 0) red[t >> 6] = wm;
  __syncthreads();
  float mb = fmaxf(fmaxf(red[0], red[1]), fmaxf(red[2], red[3]));
  float e = __expf(s - mb);
  el[a * 20 + b] = e;
  float ws2 = e;
#pragma unroll
  for (int off = 32; off; off >>= 1) ws2 += __shfl_xor(ws2, off, 64);
  if ((t & 63) == 0) red[8 + (t >> 6)] = ws2;
  __syncthreads();
  float db = red[8] + red[9] + red[10] + red[11];

  // pass 2: thread t owns feature k=t (static register indexing ONLY)
  float qv[16];
#pragma unroll
  for (int j = 0; j < 16; ++j) qv[j] = Ql[j * 260 + t];
  float rk = 0.f;
#pragma unroll 4
  for (int i = 0; i < 16; ++i) {
    float pv = Pl[i * 260 + t];
    const float* erow = &el[i * 20];
#pragma unroll
    for (int j4 = 0; j4 < 4; ++j4) {
      float4 e4 = *(const float4*)&erow[j4 * 4];
      rk += e4.x * fmaxf(pv + qv[j4 * 4 + 0], 0.f);
      rk += e4.y * fmaxf(pv + qv[j4 * 4 + 1], 0.f);
      rk += e4.z * fmaxf(pv + qv[j4 * 4 + 2], 0.f);
      rk += e4.w * fmaxf(pv + qv[j4 * 4 + 3], 0.f);
    }
  }
  sk[t] = rk;
  __syncthreads();
  {
    int h = t & 63, q = t >> 6;
    float s2 = 0.f;
    for (int k = q * 64; k < q * 64 + 64; ++k) s2 += sk[k] * ce_w2[k * 64 + h];
    sbl[q * 64 + h] = s2;
  }
  __syncthreads();
  int blk = byy * 32 + bxx;
  if (t < 64) spart[blk * 64 + t] = sbl[t] + sbl[64 + t] + sbl[128 + t] + sbl[192 + t];
  if (t == 0) { mpart[blk] = mb; dpart[blk] = db; }
}

// ============================== mega kernel ===============================
// 1120 blocks, ONE job each: 0..63 H1 gemm, 64..79 tf, 80..95 cf4,
// 96..1119 pair 16x16 tiles. No atomics, no fences (R2 lesson).
struct MegaArgs {
  const float *P, *Q, *b1, *ce_w2, *wclg;
  float *mpart, *dpart, *spart;
  GD gH1, gTf, gCf;
};

__global__ __launch_bounds__(256) void mega_k(MegaArgs a) {
  __shared__ __align__(16) char smem[MEGA_SMEM];
  int b = blockIdx.x;
  if (b < 64) {
    gemm_body(smem, a.gH1, b & 3, b >> 2);
  } else if (b < 80) {
    gemm_body(smem, a.gTf, 0, b - 64);
  } else if (b < 96) {
    gemm_body(smem, a.gCf, 0, b - 80);
  } else {
    int p = b - 96;
    pair_body(smem, a.P, a.Q, a.b1, a.ce_w2, a.wclg,
              a.mpart, a.dpart, a.spart, p >> 5, p & 31);
  }
}

// ======================= mini kernel (3 blocks x 1024) ====================
// block 0: H2 finalize (global max over 1024 tiles, D, H2row)
// block 1: h3 prefix mean     block 2: colsum -> h4vec
__global__ __launch_bounds__(1024) void mini_k(
    const float* __restrict__ mpart, const float* __restrict__ dpart,
    const float* __restrict__ spart, const float* __restrict__ ce_b2,
    float* __restrict__ H2row,
    const float* __restrict__ tf, float* __restrict__ H3,
    const float* __restrict__ cf4, float* __restrict__ h4vec) {
  __shared__ float A[1024];
  __shared__ float Bsh[1024];
  __shared__ float segsum[16][65];
  int b = blockIdx.x, t = threadIdx.x;
  if (b == 0) {
    float mv = mpart[t];
    A[t] = mv; __syncthreads();
    for (int s = 512; s; s >>= 1) { if (t < s) A[t] = fmaxf(A[t], A[t + s]); __syncthreads(); }
    float M = A[0];
    __syncthreads();
    float e = __expf(mv - M);
    Bsh[t] = e;
    A[t] = e * dpart[t];
    __syncthreads();
    for (int s = 512; s; s >>= 1) { if (t < s) A[t] += A[t + s]; __syncthreads(); }
    float D = A[0];
    __syncthreads();
    int h = t & 63, g = t >> 6;
    float s2 = 0.f;
    for (int b2 = g * 64; b2 < g * 64 + 64; ++b2) s2 += Bsh[b2] * spart[b2 * 64 + h];
    A[t] = s2;
    __syncthreads();
    for (int p = 8; p; p >>= 1) { if (g < p) A[g * 64 + h] += A[(g + p) * 64 + h]; __syncthreads(); }
    if (t < 64) H2row[t] = A[t] / D + ce_b2[t];
  } else if (b == 1) {
    // H3[i] = mean(tf[0..i]) (uniform causal softmax; see R1 derivation)
    int h = t & 63, g = t >> 6;
    float vals[32];
    float run = 0.f;
#pragma unroll
    for (int r = 0; r < 32; ++r) { run += tf[(g * 32 + r) * 64 + h]; vals[r] = run; }
    segsum[g][h] = run;
    __syncthreads();
    float off = 0.f;
    for (int gg = 0; gg < g; ++gg) off += segsum[gg][h];
#pragma unroll
    for (int r = 0; r < 32; ++r) {
      int i = g * 32 + r;
      H3[i * 64 + h] = (vals[r] + off) / (float)(i + 1);
    }
  } else {
    int h = t & 63, g = t >> 6;
    float s = 0.f;
    for (int r = 0; r < 32; ++r) s += cf4[(g * 32 + r) * 64 + h];
    A[g * 64 + h] = s;
    __syncthreads();
    for (int p = 8; p; p >>= 1) { if (g < p) A[g * 64 + h] += A[(g + p) * 64 + h]; __syncthreads(); }
    if (t < 64) h4vec[t] = A[t];
  }
}

// ---------------- layernorm + elu ----------------
__global__ void ln_elu_kernel(const float* __restrict__ X, const float* __restrict__ g,
                              const float* __restrict__ b, float* __restrict__ out) {
  __shared__ float red[256];
  int i = blockIdx.x, tid = threadIdx.x;
  float x = X[i * 256 + tid];
  red[tid] = x; __syncthreads();
  for (int s = 128; s; s >>= 1) { if (tid < s) red[tid] += red[tid + s]; __syncthreads(); }
  float mu = red[0] * (1.f / 256.f);
  __syncthreads();
  float d = x - mu;
  red[tid] = d * d; __syncthreads();
  for (int s = 128; s; s >>= 1) { if (tid < s) red[tid] += red[tid + s]; __syncthreads(); }
  float var = red[0] * (1.f / 256.f);
  float y = d / sqrtf(var + EPSV) * g[tid] + b[tid];
  out[i * 256 + tid] = (y > 0.f) ? y : (expf(y) - 1.f);
}

static GD mkgd(const float* A, const float* A2, const float* A3, const float* A4,
               const int* I, const float* B, const float* bias, float* C,
               int M, int K, int Nn, int mode, int act) {
  GD g{A, A2, A3, A4, I, B, bias, C, 0, 0, 0, 0, 0, 0, M, K, Nn, mode, act};
  return g;
}

extern "C" void kernel_launch(void* const* d_in, const int* in_sizes, int n_in,
                              void* d_out, int out_size, void* d_ws, size_t ws_size,
                              hipStream_t stream) {
  const float* V      = (const float*)d_in[0];
  const int*   adj    = (const int*)  d_in[1];
  const float* ph     = (const float*)d_in[2];
  const float* W1     = (const float*)d_in[3];
  const float* a_std1 = (const float*)d_in[5];
  const float* ce_w1  = (const float*)d_in[6];
  const float* ce_b1  = (const float*)d_in[7];
  const float* ce_w2  = (const float*)d_in[8];
  const float* ce_b2  = (const float*)d_in[9];
  const float* a_c0   = (const float*)d_in[10];
  const float* a_c1   = (const float*)d_in[11];
  const float* te_w1  = (const float*)d_in[12];
  const float* te_b1  = (const float*)d_in[13];
  const float* te_w2  = (const float*)d_in[14];
  const float* te_b2  = (const float*)d_in[15];
  const float* co_w1  = (const float*)d_in[18];
  const float* co_b1  = (const float*)d_in[19];
  const float* co_w2  = (const float*)d_in[20];
  const float* co_b2  = (const float*)d_in[21];
  const float* W2     = (const float*)d_in[24];
  const float* Wo     = (const float*)d_in[25];
  const float* bo     = (const float*)d_in[26];
  const float* ln_g   = (const float*)d_in[27];
  const float* ln_b   = (const float*)d_in[28];
  float* out = (float*)d_out;

  float* ws = (float*)d_ws;
  size_t off = 0;
  auto alloc = [&](size_t n) { float* p = ws + off; off += (n + 15) & ~(size_t)15; return p; };

  float* Pb     = alloc(512 * 256);
  float* Qb     = alloc(512 * 256);
  float* tfh    = alloc(512 * 256);
  float* cf4h   = alloc(512 * 256);
  float* H1     = alloc(512 * 256);
  float* T2     = alloc(512 * 256);
  float* tf     = alloc(512 * 64);
  float* cf4    = alloc(512 * 64);
  float* H3     = alloc(512 * 64);
  float* spart  = alloc(1024 * 64);
  float* mpart  = alloc(1024);
  float* dpart  = alloc(1024);
  float* expwsc = alloc(512);
  float* H2row  = alloc(64);
  float* h4vec  = alloc(64);
  // bf16 hi/lo planes (u16 counts / 2 = float counts)
  u16* Wh1t_h = (u16*)alloc(65536);   // [256][512]
  u16* Wh1t_l = (u16*)alloc(65536);
  u16* Wf_h   = (u16*)alloc(57344);   // [256][448]
  u16* Wf_l   = (u16*)alloc(57344);
  u16* tw2h   = (u16*)alloc(8192);    // [64][256]
  u16* tw2l   = (u16*)alloc(8192);
  u16* cw2h   = (u16*)alloc(8192);
  u16* cw2l   = (u16*)alloc(8192);
  float* wclg = alloc(256);
  (void)ws_size; (void)in_sizes; (void)n_in; (void)out_size;

  // ---- launch 1: six leading GEMMs + wsc slice + converters ----
  GD7 sA;
  sA.d[0] = mkgd(V, 0, 0, 0, 0, W1, 0, 0, 512, 256, 256, 0, 0);
  sA.d[0].Cth = Wh1t_h; sA.d[0].Ctl = Wh1t_l; sA.d[0].Ckp = 512;
  sA.d[1] = mkgd(V, 0, 0, 0, 0, ce_w1, 0, Pb, 512, 256, 256, 0, 0);
  sA.d[2] = mkgd(V, 0, 0, 0, 0, ce_w1 + 256 * 256, 0, Qb, 512, 256, 256, 0, 0);
  sA.d[3] = mkgd(V, ph, 0, 0, 0, te_w1, te_b1, tfh, 512, 512, 256, 1, 1);
  sA.d[4] = mkgd(V, 0, 0, 0, adj, co_w1, co_b1, cf4h, 512, 768, 256, 2, 1);
  sA.d[5] = mkgd(W2, 0, 0, 0, 0, Wo, 0, 0, 385, 256, 256, 0, 0);
  sA.d[5].Cth = Wf_h; sA.d[5].Ctl = Wf_l; sA.d[5].Ckp = 448;
  sA.d[6] = mkgd(W1, a_std1, V, 0, 0, 0, 0, expwsc, 512, 256, 1, 6, 0);
  sA.tw2 = te_w2; sA.cw2 = co_w2; sA.ce_w2 = ce_w2; sA.a_c0 = a_c0; sA.a_c1 = a_c1;
  sA.tw2h = tw2h; sA.tw2l = tw2l; sA.cw2h = cw2h; sA.cw2l = cw2l;
  sA.wfh = Wf_h; sA.wfl = Wf_l; sA.wclg = wclg;
  gemm7_k<<<dim3(4, 16, 7), 256, 0, stream>>>(sA);

  // ---- launch 2: H1 + tf + cf4 gemms + 1024 pair tiles ----
  MegaArgs ma;
  ma.P = Pb; ma.Q = Qb; ma.b1 = ce_b1; ma.ce_w2 = ce_w2; ma.wclg = wclg;
  ma.mpart = mpart; ma.dpart = dpart; ma.spart = spart;
  ma.gH1 = mkgd(0, expwsc, 0, 0, adj, 0, 0, H1, 512, 512, 256, 4, 0);
  ma.gH1.Bth = Wh1t_h; ma.gH1.Btl = Wh1t_l; ma.gH1.Bkp = 512;
  ma.gTf = mkgd(tfh, 0, 0, 0, 0, 0, te_b2, tf, 512, 256, 64, 0, 0);
  ma.gTf.Bth = tw2h; ma.gTf.Btl = tw2l; ma.gTf.Bkp = 256;
  ma.gCf = mkgd(cf4h, 0, 0, 0, 0, 0, co_b2, cf4, 512, 256, 64, 0, 0);
  ma.gCf.Bth = cw2h; ma.gCf.Btl = cw2l; ma.gCf.Bkp = 256;
  mega_k<<<1120, 256, 0, stream>>>(ma);

  // ---- launch 3: H2 finalize + h3 prefix mean + colsum ----
  mini_k<<<3, 1024, 0, stream>>>(mpart, dpart, spart, ce_b2, H2row, tf, H3, cf4, h4vec);

  // ---- launch 4: T2 = virtual-Hc @ Wfused + bo ----
  GD gF = mkgd(H1, H2row, H3, h4vec, 0, 0, bo, T2, 512, 385, 256, 3, 0);
  gF.Bth = Wf_h; gF.Btl = Wf_l; gF.Bkp = 448;
  gemm1_k<<<dim3(4, 16), 256, 0, stream>>>(gF);

  // ---- launch 5: layernorm + elu ----
  ln_elu_kernel<<<512, 256, 0, stream>>>(T2, ln_g, ln_b, out);
}